// Round 9
// baseline (258.247 us; speedup 1.0000x reference)
//
#include <hip/hip_runtime.h>
#include <math.h>

#define EMBED 1024
#define NHEAD 16
#define HDIM  64
#define SEQT  2048
#define BATCH 4

typedef __bf16 bf16x4 __attribute__((ext_vector_type(4)));
typedef __bf16 bf16x8 __attribute__((ext_vector_type(8)));
typedef float  f32x4  __attribute__((ext_vector_type(4)));

#define AS1 __attribute__((address_space(1)))
#define AS3 __attribute__((address_space(3)))
// async global->LDS, 16B per lane (guide §5: width=16, m97-verified)
#define GLD_LDS16(gp, lp) __builtin_amdgcn_global_load_lds( \
    (const AS1 unsigned int*)(gp), (AS3 unsigned int*)(lp), 16, 0, 0)

// log2(e) / sqrt(HDIM): folded into Q at QKV-epilogue so scores are exp2-ready
#define QSCALE 0.180336880f

// raw barrier (NO implicit vmcnt(0) drain, unlike __syncthreads) + sched fences
#define BAR do { __builtin_amdgcn_sched_barrier(0); \
                 __builtin_amdgcn_s_barrier(); \
                 __builtin_amdgcn_sched_barrier(0); } while (0)

// native cast (v_cvt_pk_bf16_f32 on gfx950)
__device__ __forceinline__ unsigned short f2bf_hw(float f) {
    union { __bf16 h; unsigned short u; } c; c.h = (__bf16)f; return c.u;
}

// one launch converts x, W_qkv, W_proj (fp32 -> bf16), in float4 units.
// Grid-stride at 2048 blocks (G11); 3145728 units = 2048*256*6 exactly.
__global__ __launch_bounds__(256)
void cvt_all(const float* __restrict__ x, const float* __restrict__ wq,
             const float* __restrict__ wp,
             unsigned short* __restrict__ xb, unsigned short* __restrict__ wqb,
             unsigned short* __restrict__ wpb)
{
    const int N1 = 2097152;            // 8192*1024/4
    const int N2 = 786432;             // 3*1024*1024/4
    const int NT = 3145728;            // N1 + N2 + 262144
    for (int i = blockIdx.x * 256 + threadIdx.x; i < NT; i += 2048 * 256) {
        const float4* src; ushort4* dst; int j;
        if (i < N1)            { src = (const float4*)x;  dst = (ushort4*)xb;  j = i; }
        else if (i < N1 + N2)  { src = (const float4*)wq; dst = (ushort4*)wqb; j = i - N1; }
        else                   { src = (const float4*)wp; dst = (ushort4*)wpb; j = i - N1 - N2; }
        float4 v = src[j];
        ushort4 o;
        o.x = f2bf_hw(v.x); o.y = f2bf_hw(v.y); o.z = f2bf_hw(v.z); o.w = f2bf_hw(v.w);
        dst[j] = o;
    }
}

// ---------------- bf16 MFMA GEMM: 128x128 / BK=32 / 3-buffer counted pipeline ---
// C[m,n] = sum_k A[m,k]*Bw[n,k] + bias[n].  R0/R4-verified geometry (2x2 waves,
// 4x4 accs of 16x16x32, conflict-free swizzle measured 0) — but the LAST
// untested sync config: counted vmcnt + multi-block TLP on this geometry.
//   - 3 buffers x 16 KiB = 48 KiB -> 3 blocks/CU (12 waves, TLP rescue that
//     R2/R3's 1-block/CU pipelines lacked)
//   - raw s_barrier (no __syncthreads: that emits vmcnt(0) lgkmcnt(0) and
//     defeats any counted wait — m97 asm analysis)
//   - iter t: issue tile t+2's 4 loads, compute tile t, then vmcnt(4):
//     tile t+1's loads landed, t+2's stay IN FLIGHT across the barrier
//     (issue->wait distance ~2 iterations). wait-then-barrier gives
//     cross-wave visibility; WAR on buf[(t+2)%3] closed by iter t-1's barrier.
template<int MODE>
__global__ __launch_bounds__(256)
void gemm_bt_pipe3(const unsigned short* __restrict__ A, const unsigned short* __restrict__ Bw,
                   const float* __restrict__ bias,
                   void* out0, void* out1, void* out2,
                   int M, int N, int K)
{
    __shared__ __align__(16) unsigned short Asm[3][128 * 32];   // 3 x 8 KB
    __shared__ __align__(16) unsigned short Bsm[3][128 * 32];   // 3 x 8 KB

    const int tid  = threadIdx.x;
    const int lane = tid & 63;
    const int wave = tid >> 6;
    const int wm = wave >> 1, wn = wave & 1;
    const int col = lane & 15, quad = lane >> 4;
    const long m0 = (long)blockIdx.y * 128, n0 = (long)blockIdx.x * 128;

    f32x4 acc[4][4];
#pragma unroll
    for (int mi = 0; mi < 4; mi++)
#pragma unroll
        for (int ni = 0; ni < 4; ni++) acc[mi][ni] = (f32x4){0.f, 0.f, 0.f, 0.f};

    // staging (R4-verified, conflicts=0): row = tid>>2 (0..63), slot tid&3,
    // source slot pre-swizzled ^((row>>1)&3) = ^((tid>>3)&3); rows +64 keep it.
    const int lrow = tid >> 2;
    const int lcol = ((tid & 3) ^ ((tid >> 3) & 3)) * 8;
    const unsigned short* Ag = A + (m0 + lrow) * K + lcol;
    const unsigned short* Bg = Bw + (n0 + lrow) * K + lcol;

#define STAGE(buf_, kk_) do { \
    GLD_LDS16(Ag + (kk_),                &Asm[buf_][0] + tid * 8); \
    GLD_LDS16(Ag + (long)64 * K + (kk_), &Asm[buf_][0] + 2048 + tid * 8); \
    GLD_LDS16(Bg + (kk_),                &Bsm[buf_][0] + tid * 8); \
    GLD_LDS16(Bg + (long)64 * K + (kk_), &Bsm[buf_][0] + 2048 + tid * 8); \
  } while (0)

    // read-side physical slot (R4-verified): quad ^ ((col>>1)&3)
    const int rsw = (quad ^ ((col >> 1) & 3)) * 8;

    // prologue: tiles 0,1 staged; wait tile 0 only (tile 1's 4 stay in flight)
    STAGE(0, 0);
    STAGE(1, 32);
    __builtin_amdgcn_s_waitcnt(0x0F74);   // vmcnt(4)
    BAR;

    const int iters = K >> 5;             // 32
    int cur = 0, stg = 2;
    for (int it = 0; it < iters; it++) {
        // issue tile it+2's staging first (overlaps this tile's compute)
        if (it + 2 < iters)
            STAGE(stg, (it + 2) * 32);

        const unsigned short* Ac = &Asm[cur][0];
        const unsigned short* Bc = &Bsm[cur][0];
        bf16x8 af[4], bf[4];
#pragma unroll
        for (int mi = 0; mi < 4; mi++)
            af[mi] = *(const bf16x8*)&Ac[(wm * 64 + mi * 16 + col) * 32 + rsw];
#pragma unroll
        for (int ni = 0; ni < 4; ni++)
            bf[ni] = *(const bf16x8*)&Bc[(wn * 64 + ni * 16 + col) * 32 + rsw];
        __builtin_amdgcn_s_setprio(1);
#pragma unroll
        for (int mi = 0; mi < 4; mi++)
#pragma unroll
            for (int ni = 0; ni < 4; ni++)
                acc[mi][ni] = __builtin_amdgcn_mfma_f32_16x16x32_bf16(af[mi], bf[ni], acc[mi][ni], 0, 0, 0);
        __builtin_amdgcn_s_setprio(0);

        // boundary: COUNTED wait — tile it+1 resident, tile it+2 in flight
        if (it + 2 < iters)      __builtin_amdgcn_s_waitcnt(0x0F74);  // vmcnt(4)
        else if (it + 1 < iters) __builtin_amdgcn_s_waitcnt(0x0F70);  // tail drain
        BAR;

        cur = (cur == 2) ? 0 : cur + 1;
        stg = (stg == 2) ? 0 : stg + 1;
    }
#undef STAGE

    // epilogue: C/D layout col=lane&15, row=quad*4+r (m89/m91-verified)
#pragma unroll
    for (int mi = 0; mi < 4; mi++) {
#pragma unroll
        for (int ni = 0; ni < 4; ni++) {
            long n = n0 + wn * 64 + ni * 16 + col;
            float bv = bias[n];
#pragma unroll
            for (int r = 0; r < 4; r++) {
                long m = m0 + wm * 64 + mi * 16 + quad * 4 + r;
                float v = acc[mi][ni][r] + bv;
                if (MODE == 0) {
                    ((float*)out0)[m * N + n] = v;
                } else {
                    int which = (int)(n >> 10);
                    int c = (int)(n & 1023);
                    int h = c >> 6, d = c & 63;
                    int b = (int)(m >> 11), t = (int)(m & 2047);
                    long bh = (long)(b * NHEAD + h);
                    if (which == 0)      ((unsigned short*)out0)[(bh * SEQT + t) * HDIM + d] = f2bf_hw(v * QSCALE);
                    else if (which == 1) ((unsigned short*)out1)[(bh * SEQT + t) * HDIM + d] = f2bf_hw(v);
                    else                 ((unsigned short*)out2)[(bh * HDIM + d) * SEQT + t] = f2bf_hw(v);
                }
            }
        }
    }
}

// ---------------- bf16 MFMA flash attention (R8: v4 + T5 + causal skip) ---------
// Q-tile 128; 4 waves × 32 q-rows. No-max softmax; S computed transposed
// (mfma(K,Q)) -> packed b64 P stores; P stored [q][k] for b128 PV A-frag reads.
#define PPAD 72

__global__ __launch_bounds__(256, 3)
void flash_attn_mfma4(const unsigned short* __restrict__ Qb,
                      const unsigned short* __restrict__ Kb,
                      const unsigned short* __restrict__ Vt,
                      unsigned short* __restrict__ Ob)
{
    __shared__ __align__(16) unsigned short P_lds[128 * PPAD];    // [q][k] 18432 B
    __shared__ __align__(16) unsigned short K_lds[2][64 * 64];    // 16 KB
    __shared__ __align__(16) unsigned short V_lds[2][64 * 64];    // 16 KB
    __shared__ __align__(16) float L_lds[128];                    // row sums

    const int tid  = threadIdx.x;
    const int lane = tid & 63;
    const int wave = tid >> 6;
    const int col  = lane & 15;
    const int quad = lane >> 4;

    const int idx = blockIdx.x;
    const int qt = 15 - (idx >> 6);      // longest blocks dispatched first
    const int hb = idx & 63;
    const int h = hb & 15, b = hb >> 4;
    const int q0 = qt * 128;
    const long bh = (long)(b * NHEAD + h);
    const unsigned short* Kbh = Kb + bh * SEQT * HDIM;
    const unsigned short* Vbh = Vt + bh * HDIM * SEQT;
    const int ktiles = 2 * qt + 2;

    const int r0 = tid >> 3,         c0 = (tid & 7) ^ (r0 & 7);
    const int r1 = (tid + 256) >> 3, c1 = (tid & 7) ^ (r1 & 7);

    bf16x8 qf[2][2];
#pragma unroll
    for (int ni = 0; ni < 2; ni++) {
        const unsigned short* qrow = Qb + (bh * SEQT + q0 + wave * 32 + ni * 16 + col) * HDIM;
        qf[ni][0] = *(const bf16x8*)(qrow + quad * 8);
        qf[ni][1] = *(const bf16x8*)(qrow + 32 + quad * 8);
    }

    GLD_LDS16(Kbh + r0 * HDIM + c0 * 8,        &K_lds[0][0] + tid * 8);
    GLD_LDS16(Kbh + r1 * HDIM + c1 * 8,        &K_lds[0][0] + 2048 + tid * 8);
    GLD_LDS16(Vbh + (long)r0 * SEQT + c0 * 8,  &V_lds[0][0] + tid * 8);
    GLD_LDS16(Vbh + (long)r1 * SEQT + c1 * 8,  &V_lds[0][0] + 2048 + tid * 8);

    f32x4 o[2][4];
#pragma unroll
    for (int mi = 0; mi < 2; mi++)
#pragma unroll
        for (int dt = 0; dt < 4; dt++) o[mi][dt] = (f32x4){0.f, 0.f, 0.f, 0.f};
    float rs[2] = {0.f, 0.f};

    const int cswz0 = quad ^ (col & 7);
    const int cswz1 = (quad + 4) ^ (col & 7);

    for (int kt = 0; kt < ktiles; kt++) {
        const int cur = kt & 1;
        const int k0 = kt * 64;
        __builtin_amdgcn_s_waitcnt(0x0F70);   // vmcnt(0)
        __syncthreads();
        if (kt + 1 < ktiles) {
            const int k0n = (kt + 1) * 64, nxt = cur ^ 1;
            GLD_LDS16(Kbh + (k0n + r0) * HDIM + c0 * 8,       &K_lds[nxt][0] + tid * 8);
            GLD_LDS16(Kbh + (k0n + r1) * HDIM + c1 * 8,       &K_lds[nxt][0] + 2048 + tid * 8);
            GLD_LDS16(Vbh + (long)r0 * SEQT + k0n + c0 * 8,   &V_lds[nxt][0] + tid * 8);
            GLD_LDS16(Vbh + (long)r1 * SEQT + k0n + c1 * 8,   &V_lds[nxt][0] + 2048 + tid * 8);
        }

        // causal skip: whole tile masked for this wave (kt=2qt+1, waves 0-1)
        if (k0 > q0 + wave * 32 + 31) continue;

        // S^T = K Q^T : A = K (m=key), B = Q (n=query). C: col=q, row=key.
        const unsigned short* Kc = &K_lds[cur][0];
        f32x4 st[4][2];
        __builtin_amdgcn_s_setprio(1);
#pragma unroll
        for (int mt = 0; mt < 4; mt++) {
            const int row = mt * 16 + col;
            bf16x8 kf0 = *(const bf16x8*)&Kc[row * 64 + cswz0 * 8];
            bf16x8 kf1 = *(const bf16x8*)&Kc[row * 64 + cswz1 * 8];
#pragma unroll
            for (int ni = 0; ni < 2; ni++) {
                f32x4 acc = (f32x4){0.f, 0.f, 0.f, 0.f};
                acc = __builtin_amdgcn_mfma_f32_16x16x32_bf16(kf0, qf[ni][0], acc, 0, 0, 0);
                acc = __builtin_amdgcn_mfma_f32_16x16x32_bf16(kf1, qf[ni][1], acc, 0, 0, 0);
                st[mt][ni] = acc;
            }
        }
        __builtin_amdgcn_s_setprio(0);
        if (kt >= 2 * qt) {                // diagonal tiles: mask key > q
#pragma unroll
            for (int mt = 0; mt < 4; mt++) {
                const int keybase = k0 + mt * 16 + quad * 4;
#pragma unroll
                for (int ni = 0; ni < 2; ni++) {
                    const int qg = q0 + wave * 32 + ni * 16 + col;
#pragma unroll
                    for (int r = 0; r < 4; r++)
                        if (keybase + r > qg) st[mt][ni][r] = -INFINITY;
                }
            }
        }

        // p = exp2(s); accumulate row-sum partials; packed b64 P-store
#pragma unroll
        for (int mt = 0; mt < 4; mt++)
#pragma unroll
            for (int ni = 0; ni < 2; ni++) {
                f32x4 p;
#pragma unroll
                for (int r = 0; r < 4; r++) p[r] = __builtin_amdgcn_exp2f(st[mt][ni][r]);
                rs[ni] += (p[0] + p[1]) + (p[2] + p[3]);
                bf16x4 pb = __builtin_convertvector(p, bf16x4);
                *(bf16x4*)&P_lds[(wave * 32 + ni * 16 + col) * PPAD + mt * 16 + quad * 4] = pb;
            }

        // PV: A = P[q][k] (wave-private rows), B = V^T
        const unsigned short* Vc = &V_lds[cur][0];
        __builtin_amdgcn_s_setprio(1);
#pragma unroll
        for (int mi = 0; mi < 2; mi++) {
            const unsigned short* prow = &P_lds[(wave * 32 + mi * 16 + col) * PPAD];
            bf16x8 pf0 = *(const bf16x8*)(prow + quad * 8);
            bf16x8 pf1 = *(const bf16x8*)(prow + 32 + quad * 8);
#pragma unroll
            for (int dt = 0; dt < 4; dt++) {
                const int row = dt * 16 + col;
                bf16x8 vf0 = *(const bf16x8*)&Vc[row * 64 + cswz0 * 8];
                bf16x8 vf1 = *(const bf16x8*)&Vc[row * 64 + cswz1 * 8];
                o[mi][dt] = __builtin_amdgcn_mfma_f32_16x16x32_bf16(pf0, vf0, o[mi][dt], 0, 0, 0);
                o[mi][dt] = __builtin_amdgcn_mfma_f32_16x16x32_bf16(pf1, vf1, o[mi][dt], 0, 0, 0);
            }
        }
        __builtin_amdgcn_s_setprio(0);
    }

    // final row-sum reduction over quads (partials partitioned by quad)
#pragma unroll
    for (int ni = 0; ni < 2; ni++) {
        rs[ni] += __shfl_xor(rs[ni], 16);
        rs[ni] += __shfl_xor(rs[ni], 32);
        if (quad == 0) L_lds[wave * 32 + ni * 16 + col] = rs[ni];
    }
    __syncthreads();
    f32x4 lf[2];
#pragma unroll
    for (int mi = 0; mi < 2; mi++)
        lf[mi] = *(const f32x4*)&L_lds[wave * 32 + mi * 16 + quad * 4];

    // epilogue: bf16 Ob[b][t][h*64+d]
#pragma unroll
    for (int mi = 0; mi < 2; mi++)
#pragma unroll
        for (int r = 0; r < 4; r++) {
            float inv = 1.f / lf[mi][r];
            int t = q0 + wave * 32 + mi * 16 + quad * 4 + r;
            unsigned short* orow = Ob + ((long)(b * SEQT + t)) * EMBED + h * HDIM;
#pragma unroll
            for (int dt = 0; dt < 4; dt++)
                orow[dt * 16 + col] = f2bf_hw(o[mi][dt][r] * inv);
        }
}

extern "C" void kernel_launch(void* const* d_in, const int* in_sizes, int n_in,
                              void* d_out, int out_size, void* d_ws, size_t ws_size,
                              hipStream_t stream)
{
    const float* x     = (const float*)d_in[0];
    const float* Wqkv  = (const float*)d_in[1];
    const float* bqkv  = (const float*)d_in[2];
    const float* Wproj = (const float*)d_in[3];
    const float* bproj = (const float*)d_in[4];
    float* out = (float*)d_out;

    const long Mbt = (long)BATCH * SEQT;                 // 8192
    const long per = (long)BATCH * NHEAD * SEQT * HDIM;  // 8,388,608 elems

    unsigned short* xb  = (unsigned short*)d_ws;
    unsigned short* wqb = xb  + per;
    unsigned short* wpb = wqb + 3 * EMBED * EMBED;
    unsigned short* Qb  = wpb + EMBED * EMBED;           // bf16 [bh][t][d], pre-scaled
    unsigned short* Kb  = Qb + per;
    unsigned short* Vt  = Kb + per;                      // bf16 [bh][d][t]
    unsigned short* Ob  = Vt + per;                      // bf16 [B,T,C]

    cvt_all<<<2048, 256, 0, stream>>>(x, Wqkv, Wproj, xb, wqb, wpb);

    dim3 g1(3 * EMBED / 128, Mbt / 128);
    gemm_bt_pipe3<1><<<g1, 256, 0, stream>>>(xb, wqb, bqkv, Qb, Kb, Vt,
                                             (int)Mbt, 3 * EMBED, EMBED);

    flash_attn_mfma4<<<1024, 256, 0, stream>>>(Qb, Kb, Vt, Ob);

    dim3 g3(EMBED / 128, Mbt / 128);
    gemm_bt_pipe3<0><<<g3, 256, 0, stream>>>(Ob, wpb, bproj, out, nullptr, nullptr,
                                             (int)Mbt, EMBED, EMBED);
}

// Round 10
// 250.156 us; speedup vs baseline: 1.0323x; 1.0323x over previous
//
#include <hip/hip_runtime.h>
#include <math.h>

#define EMBED 1024
#define NHEAD 16
#define HDIM  64
#define SEQT  2048
#define BATCH 4

typedef __bf16 bf16x4 __attribute__((ext_vector_type(4)));
typedef __bf16 bf16x8 __attribute__((ext_vector_type(8)));
typedef float  f32x4  __attribute__((ext_vector_type(4)));

#define AS1 __attribute__((address_space(1)))
#define AS3 __attribute__((address_space(3)))
// async global->LDS, 16B per lane (guide §5: width=16, m97-verified)
#define GLD_LDS16(gp, lp) __builtin_amdgcn_global_load_lds( \
    (const AS1 unsigned int*)(gp), (AS3 unsigned int*)(lp), 16, 0, 0)

// log2(e) / sqrt(HDIM): folded into Q at QKV-epilogue so scores are exp2-ready
#define QSCALE 0.180336880f

// native cast (v_cvt_pk_bf16_f32 on gfx950)
__device__ __forceinline__ unsigned short f2bf_hw(float f) {
    union { __bf16 h; unsigned short u; } c; c.h = (__bf16)f; return c.u;
}

// one launch converts x, W_qkv, W_proj (fp32 -> bf16), in float4 units
__global__ __launch_bounds__(256)
void cvt_all(const float* __restrict__ x, const float* __restrict__ wq,
             const float* __restrict__ wp,
             unsigned short* __restrict__ xb, unsigned short* __restrict__ wqb,
             unsigned short* __restrict__ wpb)
{
    const int N1 = 2097152;            // 8192*1024/4
    const int N2 = 786432;             // 3*1024*1024/4
    int i = blockIdx.x * 256 + threadIdx.x;
    const float4* src; ushort4* dst; int j;
    if (i < N1)            { src = (const float4*)x;  dst = (ushort4*)xb;  j = i; }
    else if (i < N1 + N2)  { src = (const float4*)wq; dst = (ushort4*)wqb; j = i - N1; }
    else                   { src = (const float4*)wp; dst = (ushort4*)wpb; j = i - N1 - N2; }
    float4 v = src[j];
    ushort4 o;
    o.x = f2bf_hw(v.x); o.y = f2bf_hw(v.y); o.z = f2bf_hw(v.z); o.w = f2bf_hw(v.w);
    dst[j] = o;
}

// ---------------- bf16 MFMA GEMM (R5: BK=64, session-best, frozen) ----------------
// 128x128 tile, BK=64, 2x2 waves, 4x4 accs x2 K-slices, drain-0 2-phase skeleton.
// FINAL after full experiment matrix:
//  - bank-conflict swizzle: conflicts 6.29M -> 0, time unchanged (R4: off critical path)
//  - BK 32->64 (half the barriers): +2% (R5)
//  - counted vmcnt + raw s_barrier pipelines: regressed at 1, 2, and 3 blocks/CU
//    (R1-R3, R9) — implicit wave-level overlap under __syncthreads drain-0 is
//    the best schedulable point at HIP source for this structure (guide m131-m141).
template<int MODE>
__global__ __launch_bounds__(256)
void gemm_bt_mfma(const unsigned short* __restrict__ A, const unsigned short* __restrict__ Bw,
                  const float* __restrict__ bias,
                  void* out0, void* out1, void* out2,
                  int M, int N, int K)
{
    __shared__ __align__(16) unsigned short Asm[2][128 * 64];   // 2 x 16 KB
    __shared__ __align__(16) unsigned short Bsm[2][128 * 64];   // 2 x 16 KB

    const int tid  = threadIdx.x;
    const int lane = tid & 63;
    const int wave = tid >> 6;
    const int wm = wave >> 1, wn = wave & 1;
    const int col = lane & 15, quad = lane >> 4;
    const long m0 = (long)blockIdx.y * 128, n0 = (long)blockIdx.x * 128;

    f32x4 acc[4][4];
#pragma unroll
    for (int mi = 0; mi < 4; mi++)
#pragma unroll
        for (int ni = 0; ni < 4; ni++) acc[mi][ni] = (f32x4){0.f, 0.f, 0.f, 0.f};

    const int srow  = tid >> 3;                    // 0..31
    const int gslot = (tid & 7) ^ (srow & 7);      // pre-swizzled source slot
    const unsigned short* Ag = A  + (m0 + srow) * K + gslot * 8;
    const unsigned short* Bg = Bw + (n0 + srow) * K + gslot * 8;

#define STAGE(buf_, kk_) do { \
    _Pragma("unroll") for (int r_ = 0; r_ < 4; r_++) { \
        GLD_LDS16(Ag + (long)(r_ * 32) * K + (kk_), &Asm[buf_][0] + r_ * 2048 + tid * 8); \
        GLD_LDS16(Bg + (long)(r_ * 32) * K + (kk_), &Bsm[buf_][0] + r_ * 2048 + tid * 8); \
    } } while (0)

    const int cs0 = ((quad    ) ^ (col & 7)) * 8;  // K-slice 0
    const int cs1 = ((quad + 4) ^ (col & 7)) * 8;  // K-slice 1

    STAGE(0, 0);

    const int iters = K >> 6;
    for (int it = 0; it < iters; it++) {
        const int cur = it & 1;
        __builtin_amdgcn_s_waitcnt(0x0F70);   // vmcnt(0): tile `it` staged
        __syncthreads();
        if (it + 1 < iters)
            STAGE(cur ^ 1, (it + 1) * 64);

        bf16x8 af[4][2], bf[4][2];
#pragma unroll
        for (int mi = 0; mi < 4; mi++) {
            const int row = wm * 64 + mi * 16 + col;
            af[mi][0] = *(const bf16x8*)&Asm[cur][row * 64 + cs0];
            af[mi][1] = *(const bf16x8*)&Asm[cur][row * 64 + cs1];
        }
#pragma unroll
        for (int ni = 0; ni < 4; ni++) {
            const int row = wn * 64 + ni * 16 + col;
            bf[ni][0] = *(const bf16x8*)&Bsm[cur][row * 64 + cs0];
            bf[ni][1] = *(const bf16x8*)&Bsm[cur][row * 64 + cs1];
        }
#pragma unroll
        for (int mi = 0; mi < 4; mi++)
#pragma unroll
            for (int ni = 0; ni < 4; ni++) {
                acc[mi][ni] = __builtin_amdgcn_mfma_f32_16x16x32_bf16(af[mi][0], bf[ni][0], acc[mi][ni], 0, 0, 0);
                acc[mi][ni] = __builtin_amdgcn_mfma_f32_16x16x32_bf16(af[mi][1], bf[ni][1], acc[mi][ni], 0, 0, 0);
            }
    }
#undef STAGE

    // epilogue: C/D layout col=lane&15, row=quad*4+r (m89/m91-verified)
#pragma unroll
    for (int mi = 0; mi < 4; mi++) {
#pragma unroll
        for (int ni = 0; ni < 4; ni++) {
            long n = n0 + wn * 64 + ni * 16 + col;
            float bv = bias[n];
#pragma unroll
            for (int r = 0; r < 4; r++) {
                long m = m0 + wm * 64 + mi * 16 + quad * 4 + r;
                float v = acc[mi][ni][r] + bv;
                if (MODE == 0) {
                    ((float*)out0)[m * N + n] = v;
                } else {
                    int which = (int)(n >> 10);
                    int c = (int)(n & 1023);
                    int h = c >> 6, d = c & 63;
                    int b = (int)(m >> 11), t = (int)(m & 2047);
                    long bh = (long)(b * NHEAD + h);
                    if (which == 0)      ((unsigned short*)out0)[(bh * SEQT + t) * HDIM + d] = f2bf_hw(v * QSCALE);
                    else if (which == 1) ((unsigned short*)out1)[(bh * SEQT + t) * HDIM + d] = f2bf_hw(v);
                    else                 ((unsigned short*)out2)[(bh * HDIM + d) * SEQT + t] = f2bf_hw(v);
                }
            }
        }
    }
}

// ---------------- bf16 MFMA flash attention (R5 session-best: v4 + T5) ----------
// Q-tile 128; 4 waves × 32 q-rows. No-max softmax; S computed transposed
// (mfma(K,Q)) -> packed b64 P stores; P stored [q][k] for b128 PV A-frag reads.
// Frozen after: T14 reg-staging@4blk spilled (R6), 32x32 reg-P neutral (R7),
// causal skip within noise (R8).
#define PPAD 72

__global__ __launch_bounds__(256, 3)
void flash_attn_mfma4(const unsigned short* __restrict__ Qb,
                      const unsigned short* __restrict__ Kb,
                      const unsigned short* __restrict__ Vt,
                      unsigned short* __restrict__ Ob)
{
    __shared__ __align__(16) unsigned short P_lds[128 * PPAD];    // [q][k] 18432 B
    __shared__ __align__(16) unsigned short K_lds[2][64 * 64];    // 16 KB
    __shared__ __align__(16) unsigned short V_lds[2][64 * 64];    // 16 KB
    __shared__ __align__(16) float L_lds[128];                    // row sums

    const int tid  = threadIdx.x;
    const int lane = tid & 63;
    const int wave = tid >> 6;
    const int col  = lane & 15;
    const int quad = lane >> 4;

    const int idx = blockIdx.x;
    const int qt = 15 - (idx >> 6);      // longest blocks dispatched first
    const int hb = idx & 63;
    const int h = hb & 15, b = hb >> 4;
    const int q0 = qt * 128;
    const long bh = (long)(b * NHEAD + h);
    const unsigned short* Kbh = Kb + bh * SEQT * HDIM;
    const unsigned short* Vbh = Vt + bh * HDIM * SEQT;
    const int ktiles = 2 * qt + 2;

    const int r0 = tid >> 3,         c0 = (tid & 7) ^ (r0 & 7);
    const int r1 = (tid + 256) >> 3, c1 = (tid & 7) ^ (r1 & 7);

    bf16x8 qf[2][2];
#pragma unroll
    for (int ni = 0; ni < 2; ni++) {
        const unsigned short* qrow = Qb + (bh * SEQT + q0 + wave * 32 + ni * 16 + col) * HDIM;
        qf[ni][0] = *(const bf16x8*)(qrow + quad * 8);
        qf[ni][1] = *(const bf16x8*)(qrow + 32 + quad * 8);
    }

    GLD_LDS16(Kbh + r0 * HDIM + c0 * 8,        &K_lds[0][0] + tid * 8);
    GLD_LDS16(Kbh + r1 * HDIM + c1 * 8,        &K_lds[0][0] + 2048 + tid * 8);
    GLD_LDS16(Vbh + (long)r0 * SEQT + c0 * 8,  &V_lds[0][0] + tid * 8);
    GLD_LDS16(Vbh + (long)r1 * SEQT + c1 * 8,  &V_lds[0][0] + 2048 + tid * 8);

    f32x4 o[2][4];
#pragma unroll
    for (int mi = 0; mi < 2; mi++)
#pragma unroll
        for (int dt = 0; dt < 4; dt++) o[mi][dt] = (f32x4){0.f, 0.f, 0.f, 0.f};
    float rs[2] = {0.f, 0.f};

    const int cswz0 = quad ^ (col & 7);
    const int cswz1 = (quad + 4) ^ (col & 7);

    for (int kt = 0; kt < ktiles; kt++) {
        const int cur = kt & 1;
        __builtin_amdgcn_s_waitcnt(0x0F70);   // vmcnt(0)
        __syncthreads();
        if (kt + 1 < ktiles) {
            const int k0n = (kt + 1) * 64, nxt = cur ^ 1;
            GLD_LDS16(Kbh + (k0n + r0) * HDIM + c0 * 8,       &K_lds[nxt][0] + tid * 8);
            GLD_LDS16(Kbh + (k0n + r1) * HDIM + c1 * 8,       &K_lds[nxt][0] + 2048 + tid * 8);
            GLD_LDS16(Vbh + (long)r0 * SEQT + k0n + c0 * 8,   &V_lds[nxt][0] + tid * 8);
            GLD_LDS16(Vbh + (long)r1 * SEQT + k0n + c1 * 8,   &V_lds[nxt][0] + 2048 + tid * 8);
        }

        // S^T = K Q^T : A = K (m=key), B = Q (n=query). C: col=q, row=key.
        const unsigned short* Kc = &K_lds[cur][0];
        f32x4 st[4][2];
        __builtin_amdgcn_s_setprio(1);
#pragma unroll
        for (int mt = 0; mt < 4; mt++) {
            const int row = mt * 16 + col;
            bf16x8 kf0 = *(const bf16x8*)&Kc[row * 64 + cswz0 * 8];
            bf16x8 kf1 = *(const bf16x8*)&Kc[row * 64 + cswz1 * 8];
#pragma unroll
            for (int ni = 0; ni < 2; ni++) {
                f32x4 acc = (f32x4){0.f, 0.f, 0.f, 0.f};
                acc = __builtin_amdgcn_mfma_f32_16x16x32_bf16(kf0, qf[ni][0], acc, 0, 0, 0);
                acc = __builtin_amdgcn_mfma_f32_16x16x32_bf16(kf1, qf[ni][1], acc, 0, 0, 0);
                st[mt][ni] = acc;
            }
        }
        __builtin_amdgcn_s_setprio(0);
        const int k0 = kt * 64;
        if (kt >= 2 * qt) {                // diagonal tiles: mask key > q
#pragma unroll
            for (int mt = 0; mt < 4; mt++) {
                const int keybase = k0 + mt * 16 + quad * 4;
#pragma unroll
                for (int ni = 0; ni < 2; ni++) {
                    const int qg = q0 + wave * 32 + ni * 16 + col;
#pragma unroll
                    for (int r = 0; r < 4; r++)
                        if (keybase + r > qg) st[mt][ni][r] = -INFINITY;
                }
            }
        }

        // p = exp2(s); accumulate row-sum partials; packed b64 P-store
#pragma unroll
        for (int mt = 0; mt < 4; mt++)
#pragma unroll
            for (int ni = 0; ni < 2; ni++) {
                f32x4 p;
#pragma unroll
                for (int r = 0; r < 4; r++) p[r] = __builtin_amdgcn_exp2f(st[mt][ni][r]);
                rs[ni] += (p[0] + p[1]) + (p[2] + p[3]);
                bf16x4 pb = __builtin_convertvector(p, bf16x4);
                *(bf16x4*)&P_lds[(wave * 32 + ni * 16 + col) * PPAD + mt * 16 + quad * 4] = pb;
            }

        // PV: A = P[q][k] (wave-private rows), B = V^T
        const unsigned short* Vc = &V_lds[cur][0];
        __builtin_amdgcn_s_setprio(1);
#pragma unroll
        for (int mi = 0; mi < 2; mi++) {
            const unsigned short* prow = &P_lds[(wave * 32 + mi * 16 + col) * PPAD];
            bf16x8 pf0 = *(const bf16x8*)(prow + quad * 8);
            bf16x8 pf1 = *(const bf16x8*)(prow + 32 + quad * 8);
#pragma unroll
            for (int dt = 0; dt < 4; dt++) {
                const int row = dt * 16 + col;
                bf16x8 vf0 = *(const bf16x8*)&Vc[row * 64 + cswz0 * 8];
                bf16x8 vf1 = *(const bf16x8*)&Vc[row * 64 + cswz1 * 8];
                o[mi][dt] = __builtin_amdgcn_mfma_f32_16x16x32_bf16(pf0, vf0, o[mi][dt], 0, 0, 0);
                o[mi][dt] = __builtin_amdgcn_mfma_f32_16x16x32_bf16(pf1, vf1, o[mi][dt], 0, 0, 0);
            }
        }
        __builtin_amdgcn_s_setprio(0);
    }

    // final row-sum reduction over quads (partials partitioned by quad)
#pragma unroll
    for (int ni = 0; ni < 2; ni++) {
        rs[ni] += __shfl_xor(rs[ni], 16);
        rs[ni] += __shfl_xor(rs[ni], 32);
        if (quad == 0) L_lds[wave * 32 + ni * 16 + col] = rs[ni];
    }
    __syncthreads();
    f32x4 lf[2];
#pragma unroll
    for (int mi = 0; mi < 2; mi++)
        lf[mi] = *(const f32x4*)&L_lds[wave * 32 + mi * 16 + quad * 4];

    // epilogue: bf16 Ob[b][t][h*64+d]
#pragma unroll
    for (int mi = 0; mi < 2; mi++)
#pragma unroll
        for (int r = 0; r < 4; r++) {
            float inv = 1.f / lf[mi][r];
            int t = q0 + wave * 32 + mi * 16 + quad * 4 + r;
            unsigned short* orow = Ob + ((long)(b * SEQT + t)) * EMBED + h * HDIM;
#pragma unroll
            for (int dt = 0; dt < 4; dt++)
                orow[dt * 16 + col] = f2bf_hw(o[mi][dt][r] * inv);
        }
}

extern "C" void kernel_launch(void* const* d_in, const int* in_sizes, int n_in,
                              void* d_out, int out_size, void* d_ws, size_t ws_size,
                              hipStream_t stream)
{
    const float* x     = (const float*)d_in[0];
    const float* Wqkv  = (const float*)d_in[1];
    const float* bqkv  = (const float*)d_in[2];
    const float* Wproj = (const float*)d_in[3];
    const float* bproj = (const float*)d_in[4];
    float* out = (float*)d_out;

    const long Mbt = (long)BATCH * SEQT;                 // 8192
    const long per = (long)BATCH * NHEAD * SEQT * HDIM;  // 8,388,608 elems

    unsigned short* xb  = (unsigned short*)d_ws;
    unsigned short* wqb = xb  + per;
    unsigned short* wpb = wqb + 3 * EMBED * EMBED;
    unsigned short* Qb  = wpb + EMBED * EMBED;           // bf16 [bh][t][d], pre-scaled
    unsigned short* Kb  = Qb + per;
    unsigned short* Vt  = Kb + per;                      // bf16 [bh][d][t]
    unsigned short* Ob  = Vt + per;                      // bf16 [B,T,C]

    cvt_all<<<12288, 256, 0, stream>>>(x, Wqkv, Wproj, xb, wqb, wpb);

    dim3 g1(3 * EMBED / 128, Mbt / 128);
    gemm_bt_mfma<1><<<g1, 256, 0, stream>>>(xb, wqb, bqkv, Qb, Kb, Vt,
                                            (int)Mbt, 3 * EMBED, EMBED);

    flash_attn_mfma4<<<1024, 256, 0, stream>>>(Qb, Kb, Vt, Ob);

    dim3 g3(EMBED / 128, Mbt / 128);
    gemm_bt_mfma<0><<<g3, 256, 0, stream>>>(Ob, wpb, bproj, out, nullptr, nullptr,
                                            (int)Mbt, EMBED, EMBED);
}